// Round 7
// baseline (204.941 us; speedup 1.0000x reference)
//
#include <hip/hip_runtime.h>
#include <hip/hip_bf16.h>
#include <math.h>

// ---------------------------------------------------------------------------
// B=8, T=1024, H=768, nh=12, Hs=64.  All matmuls bf16 MFMA, fp32 accum.
// ws: xb[8192*768]bf16 | Wta[2304*768]bf16 (n-major) | Wtp[768*768]bf16 (n-major)
//     qkvb[8192*2304]bf16 | attb[8192*768]bf16
// ---------------------------------------------------------------------------

typedef __attribute__((ext_vector_type(4))) float  f32x4;
typedef __attribute__((ext_vector_type(8))) short  bf16x8;
typedef __attribute__((ext_vector_type(4))) short  bf16x4;
typedef __attribute__((ext_vector_type(4))) unsigned int u32x4;

__device__ __forceinline__ unsigned short f2bf(float f) {
    union { float f; unsigned u; } v; v.f = f;
    unsigned r = (v.u + 0x7FFFu + ((v.u >> 16) & 1u)) >> 16;   // RNE
    return (unsigned short)r;
}

// packed f32 -> bf16 pair converts (v_cvt_pk_bf16_f32)
__device__ __forceinline__ bf16x4 pk4(float a, float b, float c, float d) {
    union { struct { __hip_bfloat162 lo, hi; } p; bf16x4 v; } u;
    u.p.lo = __float22bfloat162_rn(make_float2(a, b));
    u.p.hi = __float22bfloat162_rn(make_float2(c, d));
    return u.v;
}

// async global->LDS, 16B per lane (dest = wave-uniform base + lane*16)
__device__ __forceinline__ void glds16(const unsigned short* g, unsigned short* l) {
    __builtin_amdgcn_global_load_lds((const __attribute__((address_space(1))) void*)g,
                                     (__attribute__((address_space(3))) void*)l, 16, 0, 0);
}

// ---- x (fp32) -> bf16, 4 elems/thread -------------------------------------
__global__ __launch_bounds__(256)
void cvt_f32_bf16(const float* __restrict__ in, unsigned short* __restrict__ out) {
    const int i = blockIdx.x * 256 + threadIdx.x;
    const float4 v = ((const float4*)in)[i];
    ushort4 o;
    o.x = f2bf(v.x); o.y = f2bf(v.y); o.z = f2bf(v.z); o.w = f2bf(v.w);
    ((ushort4*)out)[i] = o;
}

// ---- W fp32 [K][N] -> Wt bf16 [N][K] (64x64 LDS tile transpose) -----------
__global__ __launch_bounds__(256)
void transpose_w(const float* __restrict__ W, unsigned short* __restrict__ Wt,
                 int K, int N) {
    __shared__ float Ts[64][65];
    const int k0 = blockIdx.x * 64, n0 = blockIdx.y * 64;
    const int t = threadIdx.x;
    const int r = t >> 4, cg = (t & 15) * 4;
#pragma unroll
    for (int p = 0; p < 4; ++p) {
        const float4 v = *(const float4*)(&W[(size_t)(k0 + r + p * 16) * N + n0 + cg]);
        Ts[r + p * 16][cg + 0] = v.x;
        Ts[r + p * 16][cg + 1] = v.y;
        Ts[r + p * 16][cg + 2] = v.z;
        Ts[r + p * 16][cg + 3] = v.w;
    }
    __syncthreads();
#pragma unroll
    for (int p = 0; p < 4; ++p) {
        const int n = n0 + r + p * 16;
        ushort4 o;
        o.x = f2bf(Ts[cg + 0][r + p * 16]);
        o.y = f2bf(Ts[cg + 1][r + p * 16]);
        o.z = f2bf(Ts[cg + 2][r + p * 16]);
        o.w = f2bf(Ts[cg + 3][r + p * 16]);
        *(ushort4*)(&Wt[(size_t)n * K + k0 + cg]) = o;
    }
}

// ---------------------------------------------------------------------------
// QKV GEMM, fat-wave variant: C = A[M,K] @ Bt[N,K]^T + bias (bf16 out).
// Block 128x256, 4 waves (2x2), wave tile 64x128 -> per BK=32 step per wave:
// 12 ds_read_b128 vs 32 MFMA (MFMA-bound, vs 8:16 LDS-bound before).
// LDS 24 KB; acc 128 VGPR -> __launch_bounds__(256,2), 2 blocks/CU.
// ---------------------------------------------------------------------------
__global__ __launch_bounds__(256, 2)
void gemm_qkv(const unsigned short* __restrict__ A, const unsigned short* __restrict__ Bt,
              const float* __restrict__ bias, unsigned short* __restrict__ C,
              int M, int N, int K) {
    __shared__ unsigned short As[128 * 32];
    __shared__ unsigned short Bs[256 * 32];

    const int t = threadIdx.x;
    const int L = t & 63, w = t >> 6;
    const int l15 = L & 15, quad = L >> 4;
    const int wy = w & 1, wx = w >> 1;
    const int m0 = blockIdx.x * 128, n0 = blockIdx.y * 256;

    const int srow = t >> 2, koff = (t & 3) * 8;     // 64 rows / glds round
    const unsigned short* ag = A + (size_t)(m0 + srow) * K + koff;
    const unsigned short* bg = Bt + (size_t)(n0 + srow) * K + koff;
    unsigned short* as0 = As + srow * 32 + koff;
    unsigned short* bs0 = Bs + srow * 32 + koff;
    const size_t gK = (size_t)64 * K;

    f32x4 acc[4][8];
#pragma unroll
    for (int mt = 0; mt < 4; ++mt)
#pragma unroll
        for (int nt = 0; nt < 8; ++nt) acc[mt][nt] = (f32x4){0.f, 0.f, 0.f, 0.f};

    for (int k0 = 0; k0 < K; k0 += 32) {
        glds16(ag + k0,          as0);
        glds16(ag + gK + k0,     as0 + 64 * 32);
        glds16(bg + k0,          bs0);
        glds16(bg + gK + k0,     bs0 + 64 * 32);
        glds16(bg + 2 * gK + k0, bs0 + 128 * 32);
        glds16(bg + 3 * gK + k0, bs0 + 192 * 32);
        __syncthreads();

        bf16x8 af[4];
#pragma unroll
        for (int mt = 0; mt < 4; ++mt)
            af[mt] = *(const bf16x8*)(As + (wy * 64 + mt * 16 + l15) * 32 + quad * 8);
#pragma unroll
        for (int nt = 0; nt < 8; ++nt) {
            const bf16x8 bfr = *(const bf16x8*)(Bs + (wx * 128 + nt * 16 + l15) * 32 + quad * 8);
#pragma unroll
            for (int mt = 0; mt < 4; ++mt)
                acc[mt][nt] = __builtin_amdgcn_mfma_f32_16x16x32_bf16(af[mt], bfr, acc[mt][nt], 0, 0, 0);
        }
        __syncthreads();
    }

    float bv[8];
#pragma unroll
    for (int nt = 0; nt < 8; ++nt) bv[nt] = bias[n0 + wx * 128 + nt * 16 + l15];
#pragma unroll
    for (int mt = 0; mt < 4; ++mt) {
        const int mrow = m0 + wy * 64 + mt * 16 + quad * 4;
#pragma unroll
        for (int r = 0; r < 4; ++r) {
            const int m = mrow + r;
#pragma unroll
            for (int nt = 0; nt < 8; ++nt)
                C[(size_t)m * N + n0 + wx * 128 + nt * 16 + l15] = f2bf(acc[mt][nt][r] + bv[nt]);
        }
    }
}

// ---------------------------------------------------------------------------
// proj GEMM (m97-style, 64x128 block): C = A[M,K] @ Bt[N,K]^T + bias (fp32).
// ---------------------------------------------------------------------------
__global__ __launch_bounds__(256)
void gemm_proj(const unsigned short* __restrict__ A, const unsigned short* __restrict__ Bt,
               const float* __restrict__ bias, float* __restrict__ C,
               int M, int N, int K) {
    __shared__ unsigned short As[64 * 32];
    __shared__ unsigned short Bs[128 * 32];

    const int t = threadIdx.x;
    const int L = t & 63, w = t >> 6;
    const int l15 = L & 15, quad = L >> 4;
    const int wy = w & 1, wx = w >> 1;
    const int m0 = blockIdx.x * 64, n0 = blockIdx.y * 128;

    const int srow = t >> 2, koff = (t & 3) * 8;
    const unsigned short* ag = A + (size_t)(m0 + srow) * K + koff;
    const unsigned short* bg = Bt + (size_t)(n0 + srow) * K + koff;
    unsigned short* as0 = As + srow * 32 + koff;
    unsigned short* bs0 = Bs + srow * 32 + koff;
    const size_t gK = (size_t)64 * K;

    f32x4 acc[2][4];
#pragma unroll
    for (int mt = 0; mt < 2; ++mt)
#pragma unroll
        for (int nt = 0; nt < 4; ++nt) acc[mt][nt] = (f32x4){0.f, 0.f, 0.f, 0.f};

    for (int k0 = 0; k0 < K; k0 += 32) {
        glds16(ag + k0,      as0);
        glds16(bg + k0,      bs0);
        glds16(bg + gK + k0, bs0 + 64 * 32);
        __syncthreads();

        bf16x8 af[2], bfr[4];
#pragma unroll
        for (int mt = 0; mt < 2; ++mt)
            af[mt] = *(const bf16x8*)(As + (wy * 32 + mt * 16 + l15) * 32 + quad * 8);
#pragma unroll
        for (int nt = 0; nt < 4; ++nt)
            bfr[nt] = *(const bf16x8*)(Bs + (wx * 64 + nt * 16 + l15) * 32 + quad * 8);
#pragma unroll
        for (int mt = 0; mt < 2; ++mt)
#pragma unroll
            for (int nt = 0; nt < 4; ++nt)
                acc[mt][nt] = __builtin_amdgcn_mfma_f32_16x16x32_bf16(af[mt], bfr[nt], acc[mt][nt], 0, 0, 0);
        __syncthreads();
    }

    float bv[4];
#pragma unroll
    for (int nt = 0; nt < 4; ++nt) bv[nt] = bias[n0 + wx * 64 + nt * 16 + l15];
#pragma unroll
    for (int mt = 0; mt < 2; ++mt) {
        const int mrow = m0 + wy * 32 + mt * 16 + quad * 4;
#pragma unroll
        for (int r = 0; r < 4; ++r) {
            const int m = mrow + r;
#pragma unroll
            for (int nt = 0; nt < 4; ++nt)
                C[(size_t)m * N + n0 + wx * 64 + nt * 16 + l15] = acc[mt][nt][r] + bv[nt];
        }
    }
}

// ---------------------------------------------------------------------------
// MFMA flash attention — occupancy-first (unchanged from round 6).
// Block = one (head, q-tile): grid 1536; head = blockIdx%96 (XCD-local);
// qt = 15 - blockIdx/96 (heavy first).  LDS 17.4 KB, single-buffered;
// register V prefetch one tile ahead.  S^T = K.Q^T (16x16x32); S^T C-regs
// are B-frags for PV = V^T.P^T (16x16x16bf16_1k).
// ---------------------------------------------------------------------------
__global__ __launch_bounds__(256)
void attn_mfma(const unsigned short* __restrict__ qkv, unsigned short* __restrict__ attb) {
    const int T = 1024, QKVW = 2304, NH = 12, H = 768;
    __shared__ unsigned short Ks[64 * 64];   // swizzled; Q staging, then K tiles
    __shared__ unsigned short Vt[64 * 72];   // V^T; also O staging in epilogue

    const int t = threadIdx.x;
    const int L = t & 63, w = t >> 6;
    const int l15 = L & 15, quad = L >> 4;
    const int bh = blockIdx.x % 96;
    const int qt = 15 - (int)(blockIdx.x / 96);
    const int h = bh % NH, b = bh / NH;
    const int q0 = qt * 64;

    const unsigned short* base = qkv + (size_t)b * T * QKVW + h * 64;

    const int g0 = t,       r0 = g0 >> 3, lc0 = (g0 & 7) ^ (r0 & 7);
    const int g1 = 256 + t, r1 = g1 >> 3, lc1 = (g1 & 7) ^ (r1 & 7);
    const int vk4 = (t & 15) * 4, vd4 = (t >> 4) * 4;
    const float SM = 0.18033688f;   // 0.125 * log2(e)

    glds16(base + (size_t)(q0 + r0) * QKVW + lc0 * 8, Ks + g0 * 8);
    glds16(base + (size_t)(q0 + r1) * QKVW + lc1 * 8, Ks + g1 * 8);
    ushort4 va0, va1, va2, va3;
    {
        const unsigned short* vb = base + 1536 + vd4;
        va0 = *(const ushort4*)(vb + (size_t)(vk4 + 0) * QKVW);
        va1 = *(const ushort4*)(vb + (size_t)(vk4 + 1) * QKVW);
        va2 = *(const ushort4*)(vb + (size_t)(vk4 + 2) * QKVW);
        va3 = *(const ushort4*)(vb + (size_t)(vk4 + 3) * QKVW);
    }
    __syncthreads();

    bf16x8 qf[2];
    {
        const int qrow = 16 * w + l15;
        qf[0] = *(const bf16x8*)(Ks + qrow * 64 + ((quad    ) ^ (qrow & 7)) * 8);
        qf[1] = *(const bf16x8*)(Ks + qrow * 64 + ((quad + 4) ^ (qrow & 7)) * 8);
    }

    f32x4 ot[4];
#pragma unroll
    for (int dt = 0; dt < 4; ++dt) ot[dt] = (f32x4){0.f, 0.f, 0.f, 0.f};
    float mrun = -1e30f, lsum = 0.f;

    for (int j0 = 0; j0 <= q0; j0 += 64) {
        __syncthreads();
        glds16(base + (size_t)(j0 + r0) * QKVW + 768 + lc0 * 8, Ks + g0 * 8);
        glds16(base + (size_t)(j0 + r1) * QKVW + 768 + lc1 * 8, Ks + g1 * 8);
        {
            ushort4 c0, c1, c2, c3;
            c0.x = va0.x; c0.y = va1.x; c0.z = va2.x; c0.w = va3.x;
            c1.x = va0.y; c1.y = va1.y; c1.z = va2.y; c1.w = va3.y;
            c2.x = va0.z; c2.y = va1.z; c2.z = va2.z; c2.w = va3.z;
            c3.x = va0.w; c3.y = va1.w; c3.z = va2.w; c3.w = va3.w;
            *(ushort4*)(Vt + (size_t)(vd4 + 0) * 72 + vk4) = c0;
            *(ushort4*)(Vt + (size_t)(vd4 + 1) * 72 + vk4) = c1;
            *(ushort4*)(Vt + (size_t)(vd4 + 2) * 72 + vk4) = c2;
            *(ushort4*)(Vt + (size_t)(vd4 + 3) * 72 + vk4) = c3;
        }
        if (j0 + 64 <= q0) {
            const unsigned short* vb = base + 1536 + vd4;
            va0 = *(const ushort4*)(vb + (size_t)(j0 + 64 + vk4 + 0) * QKVW);
            va1 = *(const ushort4*)(vb + (size_t)(j0 + 64 + vk4 + 1) * QKVW);
            va2 = *(const ushort4*)(vb + (size_t)(j0 + 64 + vk4 + 2) * QKVW);
            va3 = *(const ushort4*)(vb + (size_t)(j0 + 64 + vk4 + 3) * QKVW);
        }
        __syncthreads();

        f32x4 st[4];
#pragma unroll
        for (int mt = 0; mt < 4; ++mt) {
            st[mt] = (f32x4){0.f, 0.f, 0.f, 0.f};
            const int krow = 16 * mt + l15;
            const bf16x8 kf0 = *(const bf16x8*)(Ks + krow * 64 + ((quad    ) ^ (krow & 7)) * 8);
            const bf16x8 kf1 = *(const bf16x8*)(Ks + krow * 64 + ((quad + 4) ^ (krow & 7)) * 8);
            st[mt] = __builtin_amdgcn_mfma_f32_16x16x32_bf16(kf0, qf[0], st[mt], 0, 0, 0);
            st[mt] = __builtin_amdgcn_mfma_f32_16x16x32_bf16(kf1, qf[1], st[mt], 0, 0, 0);
        }

        if (j0 == q0) {
            const int qin = 16 * w + l15;
#pragma unroll
            for (int mt = 0; mt < 4; ++mt)
#pragma unroll
                for (int r = 0; r < 4; ++r)
                    if (16 * mt + 4 * quad + r > qin) st[mt][r] = -1e30f;
        }

        float nm = st[0][0];
#pragma unroll
        for (int mt = 0; mt < 4; ++mt)
#pragma unroll
            for (int r = 0; r < 4; ++r) nm = fmaxf(nm, st[mt][r]);
        nm = fmaxf(nm, __shfl_xor(nm, 16, 64));
        nm = fmaxf(nm, __shfl_xor(nm, 32, 64));
        const float mnew = fmaxf(mrun, nm);
        const float alpha = __builtin_amdgcn_exp2f((mrun - mnew) * SM);
        float ps[4][4];
        float rs = 0.f;
#pragma unroll
        for (int mt = 0; mt < 4; ++mt)
#pragma unroll
            for (int r = 0; r < 4; ++r) {
                const float p = __builtin_amdgcn_exp2f((st[mt][r] - mnew) * SM);
                ps[mt][r] = p; rs += p;
            }
        rs += __shfl_xor(rs, 16, 64);
        rs += __shfl_xor(rs, 32, 64);
        lsum = lsum * alpha + rs;
        mrun = mnew;
#pragma unroll
        for (int dt = 0; dt < 4; ++dt) {
            ot[dt][0] *= alpha; ot[dt][1] *= alpha; ot[dt][2] *= alpha; ot[dt][3] *= alpha;
        }

        bf16x4 pf[4];
#pragma unroll
        for (int c = 0; c < 4; ++c)
            pf[c] = pk4(ps[c][0], ps[c][1], ps[c][2], ps[c][3]);

#pragma unroll
        for (int c = 0; c < 4; ++c)
#pragma unroll
            for (int dt = 0; dt < 4; ++dt) {
                const bf16x4 vf = *(const bf16x4*)(Vt + (size_t)(16 * dt + l15) * 72 + 16 * c + 4 * quad);
                ot[dt] = __builtin_amdgcn_mfma_f32_16x16x16bf16_1k(vf, pf[c], ot[dt], 0, 0, 0);
            }
    }

    __syncthreads();
    const float inv = 1.0f / lsum;
#pragma unroll
    for (int dt = 0; dt < 4; ++dt)
#pragma unroll
        for (int r = 0; r < 4; ++r)
            Vt[(16 * w + l15) * 72 + 16 * dt + 4 * quad + r] = f2bf(ot[dt][r] * inv);
    __syncthreads();
    {
        const int row = t & 63, hf = t >> 6;
        const u32x4 v0 = *(const u32x4*)(Vt + row * 72 + hf * 16);
        const u32x4 v1 = *(const u32x4*)(Vt + row * 72 + hf * 16 + 8);
        unsigned short* dst = attb + (size_t)(b * T + q0 + row) * H + h * 64 + hf * 16;
        *(u32x4*)dst = v0; *(u32x4*)(dst + 8) = v1;
    }
}

extern "C" void kernel_launch(void* const* d_in, const int* in_sizes, int n_in,
                              void* d_out, int out_size, void* d_ws, size_t ws_size,
                              hipStream_t stream) {
    const float* x      = (const float*)d_in[0];
    const float* W_attn = (const float*)d_in[1];
    const float* b_attn = (const float*)d_in[2];
    const float* W_proj = (const float*)d_in[3];
    const float* b_proj = (const float*)d_in[4];
    float* out = (float*)d_out;

    const int Bn = 8, T = 1024, H = 768, NH = 12;
    const int M = Bn * T;            // 8192
    const int N1 = 3 * H;            // 2304

    unsigned short* xb   = (unsigned short*)d_ws;                 // M*H
    unsigned short* Wta  = xb + (size_t)M * H;                    // N1*H (n-major)
    unsigned short* Wtp  = Wta + (size_t)N1 * H;                  // H*H  (n-major)
    unsigned short* qkvb = Wtp + (size_t)H * H;                   // M*N1
    unsigned short* attb = qkvb + (size_t)M * N1;                 // M*H

    dim3 blk(256);

    cvt_f32_bf16<<<dim3((M * H) / 1024), blk, 0, stream>>>(x, xb);
    transpose_w<<<dim3(H / 64, N1 / 64), blk, 0, stream>>>(W_attn, Wta, H, N1);
    transpose_w<<<dim3(H / 64, H / 64), blk, 0, stream>>>(W_proj, Wtp, H, H);

    gemm_qkv<<<dim3(M / 128, N1 / 256), blk, 0, stream>>>(xb, Wta, b_attn, qkvb, M, N1, H);

    attn_mfma<<<dim3(16 * 96), blk, 0, stream>>>(qkvb, attb);

    gemm_proj<<<dim3(M / 64, H / 128), blk, 0, stream>>>(attb, Wtp, b_proj, out, M, H, H);
}

// Round 8
// 195.284 us; speedup vs baseline: 1.0494x; 1.0494x over previous
//
#include <hip/hip_runtime.h>
#include <hip/hip_bf16.h>
#include <math.h>

// ---------------------------------------------------------------------------
// B=8, T=1024, H=768, nh=12, Hs=64.  All matmuls bf16 MFMA, fp32 accum.
// ws: xb[8192*768]bf16 | Wta[2304*768]bf16 (n-major) | Wtp[768*768]bf16 (n-major)
//     qkvb[8192*2304]bf16 | attb[8192*768]bf16
// ---------------------------------------------------------------------------

typedef __attribute__((ext_vector_type(4))) float  f32x4;
typedef __attribute__((ext_vector_type(8))) short  bf16x8;
typedef __attribute__((ext_vector_type(4))) short  bf16x4;
typedef __attribute__((ext_vector_type(4))) unsigned int u32x4;

__device__ __forceinline__ unsigned short f2bf(float f) {
    union { float f; unsigned u; } v; v.f = f;
    unsigned r = (v.u + 0x7FFFu + ((v.u >> 16) & 1u)) >> 16;   // RNE
    return (unsigned short)r;
}

// packed f32 -> bf16 pair converts (v_cvt_pk_bf16_f32)
__device__ __forceinline__ bf16x4 pk4(float a, float b, float c, float d) {
    union { struct { __hip_bfloat162 lo, hi; } p; bf16x4 v; } u;
    u.p.lo = __float22bfloat162_rn(make_float2(a, b));
    u.p.hi = __float22bfloat162_rn(make_float2(c, d));
    return u.v;
}

// async global->LDS, 16B per lane (dest = wave-uniform base + lane*16)
__device__ __forceinline__ void glds16(const unsigned short* g, unsigned short* l) {
    __builtin_amdgcn_global_load_lds((const __attribute__((address_space(1))) void*)g,
                                     (__attribute__((address_space(3))) void*)l, 16, 0, 0);
}

// ---------------------------------------------------------------------------
// Fused prep: grid-partitioned  [0,6144): x->bf16  |  [6144,6576): W_attn^T
// [6576,6720): W_proj^T.   Transposes: 64x64 fp32 LDS tile, bf16 out n-major.
// ---------------------------------------------------------------------------
__global__ __launch_bounds__(256)
void prep_kernel(const float* __restrict__ x, const float* __restrict__ W_attn,
                 const float* __restrict__ W_proj,
                 unsigned short* __restrict__ xb, unsigned short* __restrict__ Wta,
                 unsigned short* __restrict__ Wtp) {
    __shared__ float Ts[64][65];
    const int t = threadIdx.x;
    const int bid = blockIdx.x;

    if (bid < 6144) {            // ---- cvt: 1024 floats per block ----
        const int i = bid * 256 + t;
        const float4 v = ((const float4*)x)[i];
        ushort4 o;
        o.x = f2bf(v.x); o.y = f2bf(v.y); o.z = f2bf(v.z); o.w = f2bf(v.w);
        ((ushort4*)xb)[i] = o;
        return;
    }

    const float* W;
    unsigned short* Wt;
    int K, N, b2;
    if (bid < 6576) { b2 = bid - 6144; W = W_attn; Wt = Wta; K = 768; N = 2304; }
    else            { b2 = bid - 6576; W = W_proj; Wt = Wtp; K = 768; N = 768;  }
    const int k0 = (b2 % 12) * 64, n0 = (b2 / 12) * 64;

    const int r = t >> 4, cg = (t & 15) * 4;
#pragma unroll
    for (int p = 0; p < 4; ++p) {
        const float4 v = *(const float4*)(&W[(size_t)(k0 + r + p * 16) * N + n0 + cg]);
        Ts[r + p * 16][cg + 0] = v.x;
        Ts[r + p * 16][cg + 1] = v.y;
        Ts[r + p * 16][cg + 2] = v.z;
        Ts[r + p * 16][cg + 3] = v.w;
    }
    __syncthreads();
#pragma unroll
    for (int p = 0; p < 4; ++p) {
        const int n = n0 + r + p * 16;
        ushort4 o;
        o.x = f2bf(Ts[cg + 0][r + p * 16]);
        o.y = f2bf(Ts[cg + 1][r + p * 16]);
        o.z = f2bf(Ts[cg + 2][r + p * 16]);
        o.w = f2bf(Ts[cg + 3][r + p * 16]);
        *(ushort4*)(&Wt[(size_t)n * K + k0 + cg]) = o;
    }
}

// ---------------------------------------------------------------------------
// m97-style bf16 MFMA GEMM (round-6 structure + XOR-swizzled LDS chunks):
// C = A[M,K] @ Bt[N,K]^T + bias.  Block (MT*32) x 128; 4 waves (2x2); BK=32.
// LDS rows 64B; physical 16B chunk cp of row r holds logical chunk cp^(r&3).
// Write side folds the xor into the GLOBAL address (glds dest must stay
// wave-uniform + lane*16); read side: 8-lane b128 groups hit each bank pair
// 2-way (free, m136) instead of 4-way (1.58x).
// ---------------------------------------------------------------------------
template <int MT>
__global__ __launch_bounds__(256)
void gemm_bf16(const unsigned short* __restrict__ A, const unsigned short* __restrict__ Bt,
               const float* __restrict__ bias, void* __restrict__ Cout,
               int M, int N, int K, int out_bf16) {
    __shared__ unsigned short As[MT * 32 * 32];
    __shared__ unsigned short Bs[128 * 32];

    const int t = threadIdx.x;
    const int L = t & 63, w = t >> 6;
    const int l15 = L & 15, quad = L >> 4;
    const int sw = l15 & 3;                 // read-side swizzle key (row&3)
    const int wy = w & 1, wx = w >> 1;
    const int m0 = blockIdx.x * (MT * 32), n0 = blockIdx.y * 128;

    const int srow = t >> 2;
    const int cp = t & 3;                   // physical chunk
    const int cl = cp ^ (srow & 3);         // logical chunk (global k-offset)
    const unsigned short* ag = A + (size_t)(m0 + srow) * K + cl * 8;
    const unsigned short* bg = Bt + (size_t)(n0 + srow) * K + cl * 8;
    unsigned short* as0 = As + srow * 32 + cp * 8;
    unsigned short* bs0 = Bs + srow * 32 + cp * 8;
    const size_t gstep = (size_t)64 * K;    // (srow+64)&3 == srow&3: same cl

    f32x4 acc[MT][4];
#pragma unroll
    for (int mt = 0; mt < MT; ++mt)
#pragma unroll
        for (int nt = 0; nt < 4; ++nt) acc[mt][nt] = (f32x4){0.f, 0.f, 0.f, 0.f};

    for (int k0 = 0; k0 < K; k0 += 32) {
        glds16(ag + k0, as0);
        if (MT == 4) glds16(ag + gstep + k0, as0 + 64 * 32);
        glds16(bg + k0, bs0);
        glds16(bg + gstep + k0, bs0 + 64 * 32);
        __syncthreads();

        bf16x8 af[MT], bfr[4];
#pragma unroll
        for (int mt = 0; mt < MT; ++mt)
            af[mt] = *(const bf16x8*)(As + (wy * (MT * 16) + mt * 16 + l15) * 32 + (quad ^ sw) * 8);
#pragma unroll
        for (int nt = 0; nt < 4; ++nt)
            bfr[nt] = *(const bf16x8*)(Bs + (wx * 64 + nt * 16 + l15) * 32 + (quad ^ sw) * 8);
#pragma unroll
        for (int mt = 0; mt < MT; ++mt)
#pragma unroll
            for (int nt = 0; nt < 4; ++nt)
                acc[mt][nt] = __builtin_amdgcn_mfma_f32_16x16x32_bf16(af[mt], bfr[nt], acc[mt][nt], 0, 0, 0);
        __syncthreads();
    }

    float bv[4];
#pragma unroll
    for (int nt = 0; nt < 4; ++nt) bv[nt] = bias[n0 + wx * 64 + nt * 16 + l15];
#pragma unroll
    for (int mt = 0; mt < MT; ++mt) {
        const int mrow = m0 + wy * (MT * 16) + mt * 16 + quad * 4;
#pragma unroll
        for (int r = 0; r < 4; ++r) {
            const int m = mrow + r;
            if (out_bf16) {
                unsigned short* C = (unsigned short*)Cout;
#pragma unroll
                for (int nt = 0; nt < 4; ++nt)
                    C[(size_t)m * N + n0 + wx * 64 + nt * 16 + l15] = f2bf(acc[mt][nt][r] + bv[nt]);
            } else {
                float* C = (float*)Cout;
#pragma unroll
                for (int nt = 0; nt < 4; ++nt)
                    C[(size_t)m * N + n0 + wx * 64 + nt * 16 + l15] = acc[mt][nt][r] + bv[nt];
            }
        }
    }
}

// ---------------------------------------------------------------------------
// MFMA flash attention — occupancy-first (unchanged from round 6).
// Block = one (head, q-tile): grid 1536; head = blockIdx%96 (XCD-local);
// qt = 15 - blockIdx/96 (heavy first).  LDS 17.4 KB, single-buffered;
// register V prefetch one tile ahead.  S^T = K.Q^T (16x16x32); S^T C-regs
// are B-frags for PV = V^T.P^T (16x16x16bf16_1k).
// ---------------------------------------------------------------------------
__global__ __launch_bounds__(256)
void attn_mfma(const unsigned short* __restrict__ qkv, unsigned short* __restrict__ attb) {
    const int T = 1024, QKVW = 2304, NH = 12, H = 768;
    __shared__ unsigned short Ks[64 * 64];   // swizzled; Q staging, then K tiles
    __shared__ unsigned short Vt[64 * 72];   // V^T; also O staging in epilogue

    const int t = threadIdx.x;
    const int L = t & 63, w = t >> 6;
    const int l15 = L & 15, quad = L >> 4;
    const int bh = blockIdx.x % 96;
    const int qt = 15 - (int)(blockIdx.x / 96);
    const int h = bh % NH, b = bh / NH;
    const int q0 = qt * 64;

    const unsigned short* base = qkv + (size_t)b * T * QKVW + h * 64;

    const int g0 = t,       r0 = g0 >> 3, lc0 = (g0 & 7) ^ (r0 & 7);
    const int g1 = 256 + t, r1 = g1 >> 3, lc1 = (g1 & 7) ^ (r1 & 7);
    const int vk4 = (t & 15) * 4, vd4 = (t >> 4) * 4;
    const float SM = 0.18033688f;   // 0.125 * log2(e)

    glds16(base + (size_t)(q0 + r0) * QKVW + lc0 * 8, Ks + g0 * 8);
    glds16(base + (size_t)(q0 + r1) * QKVW + lc1 * 8, Ks + g1 * 8);
    ushort4 va0, va1, va2, va3;
    {
        const unsigned short* vb = base + 1536 + vd4;
        va0 = *(const ushort4*)(vb + (size_t)(vk4 + 0) * QKVW);
        va1 = *(const ushort4*)(vb + (size_t)(vk4 + 1) * QKVW);
        va2 = *(const ushort4*)(vb + (size_t)(vk4 + 2) * QKVW);
        va3 = *(const ushort4*)(vb + (size_t)(vk4 + 3) * QKVW);
    }
    __syncthreads();

    bf16x8 qf[2];
    {
        const int qrow = 16 * w + l15;
        qf[0] = *(const bf16x8*)(Ks + qrow * 64 + ((quad    ) ^ (qrow & 7)) * 8);
        qf[1] = *(const bf16x8*)(Ks + qrow * 64 + ((quad + 4) ^ (qrow & 7)) * 8);
    }

    f32x4 ot[4];
#pragma unroll
    for (int dt = 0; dt < 4; ++dt) ot[dt] = (f32x4){0.f, 0.f, 0.f, 0.f};
    float mrun = -1e30f, lsum = 0.f;

    for (int j0 = 0; j0 <= q0; j0 += 64) {
        __syncthreads();
        glds16(base + (size_t)(j0 + r0) * QKVW + 768 + lc0 * 8, Ks + g0 * 8);
        glds16(base + (size_t)(j0 + r1) * QKVW + 768 + lc1 * 8, Ks + g1 * 8);
        {
            ushort4 c0, c1, c2, c3;
            c0.x = va0.x; c0.y = va1.x; c0.z = va2.x; c0.w = va3.x;
            c1.x = va0.y; c1.y = va1.y; c1.z = va2.y; c1.w = va3.y;
            c2.x = va0.z; c2.y = va1.z; c2.z = va2.z; c2.w = va3.z;
            c3.x = va0.w; c3.y = va1.w; c3.z = va2.w; c3.w = va3.w;
            *(ushort4*)(Vt + (size_t)(vd4 + 0) * 72 + vk4) = c0;
            *(ushort4*)(Vt + (size_t)(vd4 + 1) * 72 + vk4) = c1;
            *(ushort4*)(Vt + (size_t)(vd4 + 2) * 72 + vk4) = c2;
            *(ushort4*)(Vt + (size_t)(vd4 + 3) * 72 + vk4) = c3;
        }
        if (j0 + 64 <= q0) {
            const unsigned short* vb = base + 1536 + vd4;
            va0 = *(const ushort4*)(vb + (size_t)(j0 + 64 + vk4 + 0) * QKVW);
            va1 = *(const ushort4*)(vb + (size_t)(j0 + 64 + vk4 + 1) * QKVW);
            va2 = *(const ushort4*)(vb + (size_t)(j0 + 64 + vk4 + 2) * QKVW);
            va3 = *(const ushort4*)(vb + (size_t)(j0 + 64 + vk4 + 3) * QKVW);
        }
        __syncthreads();

        f32x4 st[4];
#pragma unroll
        for (int mt = 0; mt < 4; ++mt) {
            st[mt] = (f32x4){0.f, 0.f, 0.f, 0.f};
            const int krow = 16 * mt + l15;
            const bf16x8 kf0 = *(const bf16x8*)(Ks + krow * 64 + ((quad    ) ^ (krow & 7)) * 8);
            const bf16x8 kf1 = *(const bf16x8*)(Ks + krow * 64 + ((quad + 4) ^ (krow & 7)) * 8);
            st[mt] = __builtin_amdgcn_mfma_f32_16x16x32_bf16(kf0, qf[0], st[mt], 0, 0, 0);
            st[mt] = __builtin_amdgcn_mfma_f32_16x16x32_bf16(kf1, qf[1], st[mt], 0, 0, 0);
        }

        if (j0 == q0) {
            const int qin = 16 * w + l15;
#pragma unroll
            for (int mt = 0; mt < 4; ++mt)
#pragma unroll
                for (int r = 0; r < 4; ++r)
                    if (16 * mt + 4 * quad + r > qin) st[mt][r] = -1e30f;
        }

        float nm = st[0][0];
#pragma unroll
        for (int mt = 0; mt < 4; ++mt)
#pragma unroll
            for (int r = 0; r < 4; ++r) nm = fmaxf(nm, st[mt][r]);
        nm = fmaxf(nm, __shfl_xor(nm, 16, 64));
        nm = fmaxf(nm, __shfl_xor(nm, 32, 64));
        const float mnew = fmaxf(mrun, nm);
        const float alpha = __builtin_amdgcn_exp2f((mrun - mnew) * SM);
        float ps[4][4];
        float rs = 0.f;
#pragma unroll
        for (int mt = 0; mt < 4; ++mt)
#pragma unroll
            for (int r = 0; r < 4; ++r) {
                const float p = __builtin_amdgcn_exp2f((st[mt][r] - mnew) * SM);
                ps[mt][r] = p; rs += p;
            }
        rs += __shfl_xor(rs, 16, 64);
        rs += __shfl_xor(rs, 32, 64);
        lsum = lsum * alpha + rs;
        mrun = mnew;
#pragma unroll
        for (int dt = 0; dt < 4; ++dt) {
            ot[dt][0] *= alpha; ot[dt][1] *= alpha; ot[dt][2] *= alpha; ot[dt][3] *= alpha;
        }

        bf16x4 pf[4];
#pragma unroll
        for (int c = 0; c < 4; ++c)
            pf[c] = pk4(ps[c][0], ps[c][1], ps[c][2], ps[c][3]);

#pragma unroll
        for (int c = 0; c < 4; ++c)
#pragma unroll
            for (int dt = 0; dt < 4; ++dt) {
                const bf16x4 vf = *(const bf16x4*)(Vt + (size_t)(16 * dt + l15) * 72 + 16 * c + 4 * quad);
                ot[dt] = __builtin_amdgcn_mfma_f32_16x16x16bf16_1k(vf, pf[c], ot[dt], 0, 0, 0);
            }
    }

    __syncthreads();
    const float inv = 1.0f / lsum;
#pragma unroll
    for (int dt = 0; dt < 4; ++dt)
#pragma unroll
        for (int r = 0; r < 4; ++r)
            Vt[(16 * w + l15) * 72 + 16 * dt + 4 * quad + r] = f2bf(ot[dt][r] * inv);
    __syncthreads();
    {
        const int row = t & 63, hf = t >> 6;
        const u32x4 v0 = *(const u32x4*)(Vt + row * 72 + hf * 16);
        const u32x4 v1 = *(const u32x4*)(Vt + row * 72 + hf * 16 + 8);
        unsigned short* dst = attb + (size_t)(b * T + q0 + row) * H + h * 64 + hf * 16;
        *(u32x4*)dst = v0; *(u32x4*)(dst + 8) = v1;
    }
}

extern "C" void kernel_launch(void* const* d_in, const int* in_sizes, int n_in,
                              void* d_out, int out_size, void* d_ws, size_t ws_size,
                              hipStream_t stream) {
    const float* x      = (const float*)d_in[0];
    const float* W_attn = (const float*)d_in[1];
    const float* b_attn = (const float*)d_in[2];
    const float* W_proj = (const float*)d_in[3];
    const float* b_proj = (const float*)d_in[4];
    float* out = (float*)d_out;

    const int Bn = 8, T = 1024, H = 768, NH = 12;
    const int M = Bn * T;            // 8192
    const int N1 = 3 * H;            // 2304

    unsigned short* xb   = (unsigned short*)d_ws;                 // M*H
    unsigned short* Wta  = xb + (size_t)M * H;                    // N1*H (n-major)
    unsigned short* Wtp  = Wta + (size_t)N1 * H;                  // H*H  (n-major)
    unsigned short* qkvb = Wtp + (size_t)H * H;                   // M*N1
    unsigned short* attb = qkvb + (size_t)M * N1;                 // M*H

    dim3 blk(256);

    prep_kernel<<<dim3(6720), blk, 0, stream>>>(x, W_attn, W_proj, xb, Wta, Wtp);

    gemm_bf16<4><<<dim3(M / 128, N1 / 128), blk, 0, stream>>>(xb, Wta, b_attn, qkvb, M, N1, H, 1);

    attn_mfma<<<dim3(16 * 96), blk, 0, stream>>>(qkvb, attb);

    gemm_bf16<2><<<dim3(M / 64, H / 128), blk, 0, stream>>>(attb, Wtp, b_proj, out, M, H, H, 0);
}

// Round 9
// 186.087 us; speedup vs baseline: 1.1013x; 1.0494x over previous
//
#include <hip/hip_runtime.h>
#include <hip/hip_bf16.h>
#include <math.h>

// ---------------------------------------------------------------------------
// B=8, T=1024, H=768, nh=12, Hs=64.  All matmuls bf16 MFMA, fp32 accum.
// ws: xb[8192*768]bf16 | Wta[2304*768]bf16 (n-major) | Wtp[768*768]bf16 (n-major)
//     qkvb[8192*2304]bf16 | attb[8192*768]bf16
// ---------------------------------------------------------------------------

typedef __attribute__((ext_vector_type(4))) float  f32x4;
typedef __attribute__((ext_vector_type(8))) short  bf16x8;
typedef __attribute__((ext_vector_type(4))) short  bf16x4;
typedef __attribute__((ext_vector_type(4))) unsigned int u32x4;

__device__ __forceinline__ unsigned short f2bf(float f) {
    union { float f; unsigned u; } v; v.f = f;
    unsigned r = (v.u + 0x7FFFu + ((v.u >> 16) & 1u)) >> 16;   // RNE
    return (unsigned short)r;
}

// packed f32 -> bf16 pair converts (v_cvt_pk_bf16_f32)
__device__ __forceinline__ bf16x4 pk4(float a, float b, float c, float d) {
    union { struct { __hip_bfloat162 lo, hi; } p; bf16x4 v; } u;
    u.p.lo = __float22bfloat162_rn(make_float2(a, b));
    u.p.hi = __float22bfloat162_rn(make_float2(c, d));
    return u.v;
}

// async global->LDS, 16B per lane (dest = wave-uniform base + lane*16;
// KEEP lane->global ascending-contiguous or the coalescer splits requests)
__device__ __forceinline__ void glds16(const unsigned short* g, unsigned short* l) {
    __builtin_amdgcn_global_load_lds((const __attribute__((address_space(1))) void*)g,
                                     (__attribute__((address_space(3))) void*)l, 16, 0, 0);
}

// ---------------------------------------------------------------------------
// Fused prep: grid-partitioned  [0,6144): x->bf16  |  [6144,6576): W_attn^T
// [6576,6720): W_proj^T.   Transposes: 64x64 fp32 LDS tile, bf16 out n-major.
// ---------------------------------------------------------------------------
__global__ __launch_bounds__(256)
void prep_kernel(const float* __restrict__ x, const float* __restrict__ W_attn,
                 const float* __restrict__ W_proj,
                 unsigned short* __restrict__ xb, unsigned short* __restrict__ Wta,
                 unsigned short* __restrict__ Wtp) {
    __shared__ float Ts[64][65];
    const int t = threadIdx.x;
    const int bid = blockIdx.x;

    if (bid < 6144) {            // ---- cvt: 1024 floats per block ----
        const int i = bid * 256 + t;
        const float4 v = ((const float4*)x)[i];
        ushort4 o;
        o.x = f2bf(v.x); o.y = f2bf(v.y); o.z = f2bf(v.z); o.w = f2bf(v.w);
        ((ushort4*)xb)[i] = o;
        return;
    }

    const float* W;
    unsigned short* Wt;
    int K, N, b2;
    if (bid < 6576) { b2 = bid - 6144; W = W_attn; Wt = Wta; K = 768; N = 2304; }
    else            { b2 = bid - 6576; W = W_proj; Wt = Wtp; K = 768; N = 768;  }
    const int k0 = (b2 % 12) * 64, n0 = (b2 / 12) * 64;

    const int r = t >> 4, cg = (t & 15) * 4;
#pragma unroll
    for (int p = 0; p < 4; ++p) {
        const float4 v = *(const float4*)(&W[(size_t)(k0 + r + p * 16) * N + n0 + cg]);
        Ts[r + p * 16][cg + 0] = v.x;
        Ts[r + p * 16][cg + 1] = v.y;
        Ts[r + p * 16][cg + 2] = v.z;
        Ts[r + p * 16][cg + 3] = v.w;
    }
    __syncthreads();
#pragma unroll
    for (int p = 0; p < 4; ++p) {
        const int n = n0 + r + p * 16;
        ushort4 o;
        o.x = f2bf(Ts[cg + 0][r + p * 16]);
        o.y = f2bf(Ts[cg + 1][r + p * 16]);
        o.z = f2bf(Ts[cg + 2][r + p * 16]);
        o.w = f2bf(Ts[cg + 3][r + p * 16]);
        *(ushort4*)(&Wt[(size_t)n * K + k0 + cg]) = o;
    }
}

// ---------------------------------------------------------------------------
// bf16 MFMA GEMM, BK=64 split-half layout: C = A[M,K] @ Bt[N,K]^T + bias.
// Block (MT*32) x 128; 4 waves (2x2); 16x16x32 mfma.
// LDS = [half][rows][32k] (64B rows, m97-proven stride; halves stacked) so
// BK=64 doubles MFMA per barrier (32/wave) without 128B-row conflicts.
// Staging keeps lane->global ascending 16B chunks (r8 lesson: don't permute).
// MT=4: As 16KB + Bs 16KB -> 3 blocks/CU.  MT=2: As 8KB.
// ---------------------------------------------------------------------------
template <int MT>
__global__ __launch_bounds__(256)
void gemm_bf16(const unsigned short* __restrict__ A, const unsigned short* __restrict__ Bt,
               const float* __restrict__ bias, void* __restrict__ Cout,
               int M, int N, int K, int out_bf16) {
    __shared__ unsigned short As[MT * 64 * 32];   // [2][MT*32 rows][32]
    __shared__ unsigned short Bs[2 * 128 * 32];   // [2][128 rows][32]

    const int t = threadIdx.x;
    const int L = t & 63, w = t >> 6;
    const int l15 = L & 15, quad = L >> 4;
    const int wy = w & 1, wx = w >> 1;
    const int m0 = blockIdx.x * (MT * 32), n0 = blockIdx.y * 128;

    const int srow = t >> 2, koff = (t & 3) * 8;
    const unsigned short* ag = A + (size_t)(m0 + srow) * K + koff;
    const unsigned short* bg = Bt + (size_t)(n0 + srow) * K + koff;
    unsigned short* as0 = As + t * 8;     // = srow*32 + koff within a section
    unsigned short* bs0 = Bs + t * 8;
    const size_t gstep = (size_t)64 * K;
    const int AH = MT * 1024;             // A half-section stride (shorts)

    f32x4 acc[MT][4];
#pragma unroll
    for (int mt = 0; mt < MT; ++mt)
#pragma unroll
        for (int nt = 0; nt < 4; ++nt) acc[mt][nt] = (f32x4){0.f, 0.f, 0.f, 0.f};

    for (int k0 = 0; k0 < K; k0 += 64) {
        // ---- stage A: MT rounds of 64 rows x 32k ----
        if (MT == 4) {
            glds16(ag + k0,              as0);            // h0, rows 0-63
            glds16(ag + gstep + k0,      as0 + 2048);     // h0, rows 64-127
            glds16(ag + k0 + 32,         as0 + 4096);     // h1, rows 0-63
            glds16(ag + gstep + k0 + 32, as0 + 6144);     // h1, rows 64-127
        } else {
            glds16(ag + k0,      as0);                    // h0
            glds16(ag + k0 + 32, as0 + 2048);             // h1
        }
        // ---- stage B: 4 rounds ----
        glds16(bg + k0,              bs0);
        glds16(bg + gstep + k0,      bs0 + 2048);
        glds16(bg + k0 + 32,         bs0 + 4096);
        glds16(bg + gstep + k0 + 32, bs0 + 6144);
        __syncthreads();

#pragma unroll
        for (int kk = 0; kk < 2; ++kk) {
            bf16x8 af[MT], bfr[4];
#pragma unroll
            for (int mt = 0; mt < MT; ++mt)
                af[mt] = *(const bf16x8*)(As + kk * AH + (wy * (MT * 16) + mt * 16 + l15) * 32 + quad * 8);
#pragma unroll
            for (int nt = 0; nt < 4; ++nt)
                bfr[nt] = *(const bf16x8*)(Bs + kk * 4096 + (wx * 64 + nt * 16 + l15) * 32 + quad * 8);
#pragma unroll
            for (int mt = 0; mt < MT; ++mt)
#pragma unroll
                for (int nt = 0; nt < 4; ++nt)
                    acc[mt][nt] = __builtin_amdgcn_mfma_f32_16x16x32_bf16(af[mt], bfr[nt], acc[mt][nt], 0, 0, 0);
        }
        __syncthreads();
    }

    float bv[4];
#pragma unroll
    for (int nt = 0; nt < 4; ++nt) bv[nt] = bias[n0 + wx * 64 + nt * 16 + l15];
#pragma unroll
    for (int mt = 0; mt < MT; ++mt) {
        const int mrow = m0 + wy * (MT * 16) + mt * 16 + quad * 4;
#pragma unroll
        for (int r = 0; r < 4; ++r) {
            const int m = mrow + r;
            if (out_bf16) {
                unsigned short* C = (unsigned short*)Cout;
#pragma unroll
                for (int nt = 0; nt < 4; ++nt)
                    C[(size_t)m * N + n0 + wx * 64 + nt * 16 + l15] = f2bf(acc[mt][nt][r] + bv[nt]);
            } else {
                float* C = (float*)Cout;
#pragma unroll
                for (int nt = 0; nt < 4; ++nt)
                    C[(size_t)m * N + n0 + wx * 64 + nt * 16 + l15] = acc[mt][nt][r] + bv[nt];
            }
        }
    }
}

// ---------------------------------------------------------------------------
// MFMA flash attention — occupancy-first (unchanged from round 6).
// Block = one (head, q-tile): grid 1536; head = blockIdx%96 (XCD-local);
// qt = 15 - blockIdx/96 (heavy first).  LDS 17.4 KB, single-buffered;
// register V prefetch one tile ahead.  S^T = K.Q^T (16x16x32); S^T C-regs
// are B-frags for PV = V^T.P^T (16x16x16bf16_1k).
// ---------------------------------------------------------------------------
__global__ __launch_bounds__(256)
void attn_mfma(const unsigned short* __restrict__ qkv, unsigned short* __restrict__ attb) {
    const int T = 1024, QKVW = 2304, NH = 12, H = 768;
    __shared__ unsigned short Ks[64 * 64];   // swizzled; Q staging, then K tiles
    __shared__ unsigned short Vt[64 * 72];   // V^T; also O staging in epilogue

    const int t = threadIdx.x;
    const int L = t & 63, w = t >> 6;
    const int l15 = L & 15, quad = L >> 4;
    const int bh = blockIdx.x % 96;
    const int qt = 15 - (int)(blockIdx.x / 96);
    const int h = bh % NH, b = bh / NH;
    const int q0 = qt * 64;

    const unsigned short* base = qkv + (size_t)b * T * QKVW + h * 64;

    const int g0 = t,       r0 = g0 >> 3, lc0 = (g0 & 7) ^ (r0 & 7);
    const int g1 = 256 + t, r1 = g1 >> 3, lc1 = (g1 & 7) ^ (r1 & 7);
    const int vk4 = (t & 15) * 4, vd4 = (t >> 4) * 4;
    const float SM = 0.18033688f;   // 0.125 * log2(e)

    glds16(base + (size_t)(q0 + r0) * QKVW + lc0 * 8, Ks + g0 * 8);
    glds16(base + (size_t)(q0 + r1) * QKVW + lc1 * 8, Ks + g1 * 8);
    ushort4 va0, va1, va2, va3;
    {
        const unsigned short* vb = base + 1536 + vd4;
        va0 = *(const ushort4*)(vb + (size_t)(vk4 + 0) * QKVW);
        va1 = *(const ushort4*)(vb + (size_t)(vk4 + 1) * QKVW);
        va2 = *(const ushort4*)(vb + (size_t)(vk4 + 2) * QKVW);
        va3 = *(const ushort4*)(vb + (size_t)(vk4 + 3) * QKVW);
    }
    __syncthreads();

    bf16x8 qf[2];
    {
        const int qrow = 16 * w + l15;
        qf[0] = *(const bf16x8*)(Ks + qrow * 64 + ((quad    ) ^ (qrow & 7)) * 8);
        qf[1] = *(const bf16x8*)(Ks + qrow * 64 + ((quad + 4) ^ (qrow & 7)) * 8);
    }

    f32x4 ot[4];
#pragma unroll
    for (int dt = 0; dt < 4; ++dt) ot[dt] = (f32x4){0.f, 0.f, 0.f, 0.f};
    float mrun = -1e30f, lsum = 0.f;

    for (int j0 = 0; j0 <= q0; j0 += 64) {
        __syncthreads();
        glds16(base + (size_t)(j0 + r0) * QKVW + 768 + lc0 * 8, Ks + g0 * 8);
        glds16(base + (size_t)(j0 + r1) * QKVW + 768 + lc1 * 8, Ks + g1 * 8);
        {
            ushort4 c0, c1, c2, c3;
            c0.x = va0.x; c0.y = va1.x; c0.z = va2.x; c0.w = va3.x;
            c1.x = va0.y; c1.y = va1.y; c1.z = va2.y; c1.w = va3.y;
            c2.x = va0.z; c2.y = va1.z; c2.z = va2.z; c2.w = va3.z;
            c3.x = va0.w; c3.y = va1.w; c3.z = va2.w; c3.w = va3.w;
            *(ushort4*)(Vt + (size_t)(vd4 + 0) * 72 + vk4) = c0;
            *(ushort4*)(Vt + (size_t)(vd4 + 1) * 72 + vk4) = c1;
            *(ushort4*)(Vt + (size_t)(vd4 + 2) * 72 + vk4) = c2;
            *(ushort4*)(Vt + (size_t)(vd4 + 3) * 72 + vk4) = c3;
        }
        if (j0 + 64 <= q0) {
            const unsigned short* vb = base + 1536 + vd4;
            va0 = *(const ushort4*)(vb + (size_t)(j0 + 64 + vk4 + 0) * QKVW);
            va1 = *(const ushort4*)(vb + (size_t)(j0 + 64 + vk4 + 1) * QKVW);
            va2 = *(const ushort4*)(vb + (size_t)(j0 + 64 + vk4 + 2) * QKVW);
            va3 = *(const ushort4*)(vb + (size_t)(j0 + 64 + vk4 + 3) * QKVW);
        }
        __syncthreads();

        f32x4 st[4];
#pragma unroll
        for (int mt = 0; mt < 4; ++mt) {
            st[mt] = (f32x4){0.f, 0.f, 0.f, 0.f};
            const int krow = 16 * mt + l15;
            const bf16x8 kf0 = *(const bf16x8*)(Ks + krow * 64 + ((quad    ) ^ (krow & 7)) * 8);
            const bf16x8 kf1 = *(const bf16x8*)(Ks + krow * 64 + ((quad + 4) ^ (krow & 7)) * 8);
            st[mt] = __builtin_amdgcn_mfma_f32_16x16x32_bf16(kf0, qf[0], st[mt], 0, 0, 0);
            st[mt] = __builtin_amdgcn_mfma_f32_16x16x32_bf16(kf1, qf[1], st[mt], 0, 0, 0);
        }

        if (j0 == q0) {
            const int qin = 16 * w + l15;
#pragma unroll
            for (int mt = 0; mt < 4; ++mt)
#pragma unroll
                for (int r = 0; r < 4; ++r)
                    if (16 * mt + 4 * quad + r > qin) st[mt][r] = -1e30f;
        }

        float nm = st[0][0];
#pragma unroll
        for (int mt = 0; mt < 4; ++mt)
#pragma unroll
            for (int r = 0; r < 4; ++r) nm = fmaxf(nm, st[mt][r]);
        nm = fmaxf(nm, __shfl_xor(nm, 16, 64));
        nm = fmaxf(nm, __shfl_xor(nm, 32, 64));
        const float mnew = fmaxf(mrun, nm);
        const float alpha = __builtin_amdgcn_exp2f((mrun - mnew) * SM);
        float ps[4][4];
        float rs = 0.f;
#pragma unroll
        for (int mt = 0; mt < 4; ++mt)
#pragma unroll
            for (int r = 0; r < 4; ++r) {
                const float p = __builtin_amdgcn_exp2f((st[mt][r] - mnew) * SM);
                ps[mt][r] = p; rs += p;
            }
        rs += __shfl_xor(rs, 16, 64);
        rs += __shfl_xor(rs, 32, 64);
        lsum = lsum * alpha + rs;
        mrun = mnew;
#pragma unroll
        for (int dt = 0; dt < 4; ++dt) {
            ot[dt][0] *= alpha; ot[dt][1] *= alpha; ot[dt][2] *= alpha; ot[dt][3] *= alpha;
        }

        bf16x4 pf[4];
#pragma unroll
        for (int c = 0; c < 4; ++c)
            pf[c] = pk4(ps[c][0], ps[c][1], ps[c][2], ps[c][3]);

#pragma unroll
        for (int c = 0; c < 4; ++c)
#pragma unroll
            for (int dt = 0; dt < 4; ++dt) {
                const bf16x4 vf = *(const bf16x4*)(Vt + (size_t)(16 * dt + l15) * 72 + 16 * c + 4 * quad);
                ot[dt] = __builtin_amdgcn_mfma_f32_16x16x16bf16_1k(vf, pf[c], ot[dt], 0, 0, 0);
            }
    }

    __syncthreads();
    const float inv = 1.0f / lsum;
#pragma unroll
    for (int dt = 0; dt < 4; ++dt)
#pragma unroll
        for (int r = 0; r < 4; ++r)
            Vt[(16 * w + l15) * 72 + 16 * dt + 4 * quad + r] = f2bf(ot[dt][r] * inv);
    __syncthreads();
    {
        const int row = t & 63, hf = t >> 6;
        const u32x4 v0 = *(const u32x4*)(Vt + row * 72 + hf * 16);
        const u32x4 v1 = *(const u32x4*)(Vt + row * 72 + hf * 16 + 8);
        unsigned short* dst = attb + (size_t)(b * T + q0 + row) * H + h * 64 + hf * 16;
        *(u32x4*)dst = v0; *(u32x4*)(dst + 8) = v1;
    }
}

extern "C" void kernel_launch(void* const* d_in, const int* in_sizes, int n_in,
                              void* d_out, int out_size, void* d_ws, size_t ws_size,
                              hipStream_t stream) {
    const float* x      = (const float*)d_in[0];
    const float* W_attn = (const float*)d_in[1];
    const float* b_attn = (const float*)d_in[2];
    const float* W_proj = (const float*)d_in[3];
    const float* b_proj = (const float*)d_in[4];
    float* out = (float*)d_out;

    const int Bn = 8, T = 1024, H = 768, NH = 12;
    const int M = Bn * T;            // 8192
    const int N1 = 3 * H;            // 2304

    unsigned short* xb   = (unsigned short*)d_ws;                 // M*H
    unsigned short* Wta  = xb + (size_t)M * H;                    // N1*H (n-major)
    unsigned short* Wtp  = Wta + (size_t)N1 * H;                  // H*H  (n-major)
    unsigned short* qkvb = Wtp + (size_t)H * H;                   // M*N1
    unsigned short* attb = qkvb + (size_t)M * N1;                 // M*H

    dim3 blk(256);

    prep_kernel<<<dim3(6720), blk, 0, stream>>>(x, W_attn, W_proj, xb, Wta, Wtp);

    gemm_bf16<4><<<dim3(M / 128, N1 / 128), blk, 0, stream>>>(xb, Wta, b_attn, qkvb, M, N1, H, 1);

    attn_mfma<<<dim3(16 * 96), blk, 0, stream>>>(qkvb, attb);

    gemm_bf16<2><<<dim3(M / 64, H / 128), blk, 0, stream>>>(attb, Wtp, b_proj, out, M, H, H, 0);
}